// Round 5
// baseline (1107.632 us; speedup 1.0000x reference)
//
#include <hip/hip_runtime.h>
#include <hip/hip_bf16.h>
#include <math.h>

// Model: B=64,S=100,D=768,H=8,P=8,FF=3072,HD=96, 4 shared layers.
//  - param path computed ONCE (layer-shared); param_bias via MFMA (R4).
//  - GEMM gemm256 (R8, proven): 256x128 tile, BK=64, 8 waves, tri-buffered
//    LDS (144KB), fine-interleaved 2-phases-per-K-tile {ds_read || stage t+2
//    || setprio+MFMA || barrier}, counted vmcnt(6) (never 0 in steady state).
//    Used for gemm<1> (N=3072, grid 600).
//  - GEMM gemm64 (R9): same schedule at BM=64 geometry for the N=768 shapes
//    (gemm<0>, gemm<2>): grid was 150 blocks @1/CU (106 CUs idle, 59% eff).
//    Now 64x128 tile, 4 waves, 72KB tri-buffer -> 2 blocks/CU, grid 600.
//    Same 6 loads/thread/K-tile -> identical vmcnt(6) accounting; same
//    chunk-XOR swizzle (key (row>>1)&7 invariant under row+32/64/96).
//  - attention per (b,h): MFMA scores (pbias C-init) + reg-softmax + MFMA PV.
//  - split-K classifier + float4-vectorized LayerNorm.

typedef __attribute__((ext_vector_type(8))) short bf16x8;
typedef __attribute__((ext_vector_type(4))) float f32x4;
typedef __attribute__((ext_vector_type(4))) short short4v;

#define BB 64
#define SS 100
#define DD 768
#define HH 8
#define HD 96
#define FF_ 3072
#define ROWS 6400           // B*S
#define LN10000 9.210340371976184f

__device__ __forceinline__ void async_copy16(void* lds_dst, const void* gsrc) {
  __builtin_amdgcn_global_load_lds(
      (const __attribute__((address_space(1))) void*)gsrc,
      (__attribute__((address_space(3))) void*)lds_dst, 16, 0, 0);
}

// ---------------- block-wide sums ----------------
__device__ __forceinline__ float block_sum256(float v, float* sbuf) {
#pragma unroll
  for (int o = 32; o > 0; o >>= 1) v += __shfl_xor(v, o, 64);
  int tid = threadIdx.x;
  __syncthreads();
  if ((tid & 63) == 0) sbuf[tid >> 6] = v;
  __syncthreads();
  return sbuf[0] + sbuf[1] + sbuf[2] + sbuf[3];
}

__device__ __forceinline__ float block_sum192(float v, float* sbuf) {
#pragma unroll
  for (int o = 32; o > 0; o >>= 1) v += __shfl_xor(v, o, 64);
  int tid = threadIdx.x;
  __syncthreads();
  if ((tid & 63) == 0) sbuf[tid >> 6] = v;
  __syncthreads();
  return sbuf[0] + sbuf[1] + sbuf[2];
}

// ---------------- fp32 [K,N] -> bf16 [N,K] transpose-convert ----------------
__global__ void convert_transpose(const float* __restrict__ in,
                                  __hip_bfloat16* __restrict__ out,
                                  int K, int N) {
  __shared__ float t[32][33];
  int n0 = blockIdx.x * 32, k0 = blockIdx.y * 32;
  int tid = threadIdx.x;
  int tx = tid & 31, ty = tid >> 5;  // ty 0..7
#pragma unroll
  for (int j = 0; j < 32; j += 8)
    t[ty + j][tx] = in[(size_t)(k0 + ty + j) * N + n0 + tx];
  __syncthreads();
#pragma unroll
  for (int j = 0; j < 32; j += 8)
    out[(size_t)(n0 + ty + j) * K + k0 + tx] = __float2bfloat16(t[tx][ty + j]);
}

// ---------------- pooled = mean_P(param_seq) -> bf16 ----------------
__global__ void pool_mean(const float* __restrict__ ps,
                          __hip_bfloat16* __restrict__ pooled) {
  int idx = blockIdx.x * 256 + threadIdx.x;  // < 6400*768
  int row = idx / DD, c = idx - row * DD;
  float s = 0.f;
#pragma unroll
  for (int p = 0; p < 8; p++) s += ps[(size_t)(row * 8 + p) * DD + c];
  pooled[idx] = __float2bfloat16(s * 0.125f);
}

// ---------------- src = template + PE ----------------
__global__ void add_pe(const float* __restrict__ t, float* __restrict__ src) {
  int idx = blockIdx.x * 256 + threadIdx.x;
  int row = idx / DD, c = idx - row * DD;
  int srow = row % SS;
  int c2 = c & ~1;
  float ang = (float)srow * expf((float)c2 * (-LN10000 / (float)DD));
  float pe = (c & 1) ? cosf(ang) : sinf(ang);
  src[idx] = t[idx] + pe;
}

// ---------------- LayerNorm over rows of 768 (192 thr, float4) ----------------
// XB16: X is bf16; RESID: add R (fp32); WB16: also write bf16 copy
template <bool XB16, bool RESID, bool WB16>
__global__ void ln_row(const float* __restrict__ Xf,
                       const __hip_bfloat16* __restrict__ Xb,
                       const float* __restrict__ R,
                       const float* __restrict__ g, const float* __restrict__ bb,
                       float* __restrict__ of, __hip_bfloat16* __restrict__ ob) {
  int row = blockIdx.x, tid = threadIdx.x;
  size_t base = (size_t)row * DD;
  int c4 = tid * 4;
  float4 v;
  if constexpr (XB16) {
    short4v xv = *(const short4v*)(Xb + base + c4);
    __hip_bfloat16* p = (__hip_bfloat16*)&xv;
    v.x = __bfloat162float(p[0]); v.y = __bfloat162float(p[1]);
    v.z = __bfloat162float(p[2]); v.w = __bfloat162float(p[3]);
  } else {
    v = *(const float4*)(Xf + base + c4);
  }
  if (RESID) {
    float4 rv = *(const float4*)(R + base + c4);
    v.x += rv.x; v.y += rv.y; v.z += rv.z; v.w += rv.w;
  }
  __shared__ float sbuf[3];
  float s = block_sum192(v.x + v.y + v.z + v.w, sbuf);
  float mean = s * (1.0f / DD);
  float dx = v.x - mean, dy = v.y - mean, dz = v.z - mean, dw = v.w - mean;
  float ss = block_sum192(dx * dx + dy * dy + dz * dz + dw * dw, sbuf);
  float rs = rsqrtf(ss * (1.0f / DD) + 1e-5f);
  float4 gv = *(const float4*)(g + c4);
  float4 bv = *(const float4*)(bb + c4);
  float4 y;
  y.x = dx * rs * gv.x + bv.x;
  y.y = dy * rs * gv.y + bv.y;
  y.z = dz * rs * gv.z + bv.z;
  y.w = dw * rs * gv.w + bv.w;
  *(float4*)(of + base + c4) = y;
  if (WB16) {
    __hip_bfloat16 hb[4] = {__float2bfloat16(y.x), __float2bfloat16(y.y),
                            __float2bfloat16(y.z), __float2bfloat16(y.w)};
    *(short4v*)(ob + base + c4) = *(short4v*)hb;
  }
}

// ---------------- param_bias via MFMA: pb.pb^T / sqrt(HD) ----------------
__launch_bounds__(256, 2)
__global__ void param_bias_mfma(const float* __restrict__ penc,
                                float* __restrict__ pbias) {
  __shared__ __align__(16) __hip_bfloat16 Qs[128][104];
  const int bh = blockIdx.x;
  const int b = bh >> 3, h = bh & 7;
  const int tid = threadIdx.x;
  const int wave = tid >> 6, lane = tid & 63;
  const int r = lane & 15, quad = lane >> 4;
  const int q8 = quad * 8;
  const int wr = (wave >> 1) * 64, wc = (wave & 1) * 64;
  const float sroot = rsqrtf(9.79795897113f);  // 96^(-1/4)
  for (int i = tid; i < 128 * HD; i += 256) {
    int s = i / HD, d = i - s * HD;
    float v = (s < SS) ? penc[(size_t)(b * SS + s) * DD + h * HD + d] : 0.f;
    Qs[s][d] = __float2bfloat16(v * sroot);
  }
  __syncthreads();
  f32x4 acc[4][4] = {};
#pragma unroll
  for (int k0 = 0; k0 < HD; k0 += 32) {
    bf16x8 af[4], bfv[4];
#pragma unroll
    for (int mi = 0; mi < 4; mi++)
      af[mi] = *(const bf16x8*)&Qs[wr + mi * 16 + r][k0 + q8];
#pragma unroll
    for (int ni = 0; ni < 4; ni++)
      bfv[ni] = *(const bf16x8*)&Qs[wc + ni * 16 + r][k0 + q8];
#pragma unroll
    for (int mi = 0; mi < 4; mi++)
#pragma unroll
      for (int ni = 0; ni < 4; ni++)
        acc[mi][ni] = __builtin_amdgcn_mfma_f32_16x16x32_bf16(af[mi], bfv[ni],
                                                              acc[mi][ni], 0, 0, 0);
  }
  float* pb = pbias + (size_t)bh * SS * SS;
#pragma unroll
  for (int mi = 0; mi < 4; mi++)
#pragma unroll
    for (int ni = 0; ni < 4; ni++) {
      int col = wc + ni * 16 + r;
      if (col < SS) {
#pragma unroll
        for (int rg = 0; rg < 4; rg++) {
          int row = wr + mi * 16 + quad * 4 + rg;
          if (row < SS) pb[row * SS + col] = acc[mi][ni][rg];
        }
      }
    }
}

// ---------------- fused MFMA attention per (b,h) ----------------
__launch_bounds__(256, 2)
__global__ void attn_fused_mfma(const float* __restrict__ src,
                                const float* __restrict__ pbias,
                                __hip_bfloat16* __restrict__ out) {
  __shared__ __align__(16) char umem[128 * 136 * 2];  // Qs[128][104] then Ps[128][136]
  __shared__ __align__(16) __hip_bfloat16 Qt[96][136];
  __shared__ float redm[2][128];
  __shared__ float reds[2][128];
  __hip_bfloat16 (*Qs)[104] = (__hip_bfloat16 (*)[104])umem;
  __hip_bfloat16 (*Ps)[136] = (__hip_bfloat16 (*)[136])umem;

  const int bh = blockIdx.x;
  const int b = bh >> 3, h = bh & 7;
  const int tid = threadIdx.x;
  const int wave = tid >> 6, lane = tid & 63;
  const int r = lane & 15, quad = lane >> 4;
  const int q8 = quad * 8;
  const int wr = (wave >> 1) * 64, wc = (wave & 1) * 64;

  const float sroot = rsqrtf(9.79795897113f);  // 96^(-1/4)
  for (int i = tid; i < SS * HD; i += 256) {
    int s = i / HD, d = i - s * HD;
    float v = src[(size_t)(b * SS + s) * DD + h * HD + d];
    Qs[s][d] = __float2bfloat16(v * sroot);
    Qt[d][s] = __float2bfloat16(v);
  }
  for (int i = tid; i < 28 * HD; i += 256) {  // zero pads
    int s = i / HD, d = i - s * HD;           // s in 0..27
    Qs[100 + s][d] = __float2bfloat16(0.f);
    Qt[d][100 + s] = __float2bfloat16(0.f);
  }

  const float* pb = pbias + (size_t)bh * SS * SS;
  bool cv[4]; int cols[4];
#pragma unroll
  for (int ni = 0; ni < 4; ni++) { cols[ni] = wc + ni * 16 + r; cv[ni] = cols[ni] < SS; }
  f32x4 acc[4][4];
#pragma unroll
  for (int mi = 0; mi < 4; mi++)
#pragma unroll
    for (int rg = 0; rg < 4; rg++) {
      int row = wr + mi * 16 + quad * 4 + rg;
#pragma unroll
      for (int ni = 0; ni < 4; ni++)
        acc[mi][ni][rg] = (row < SS && cv[ni]) ? pb[row * SS + cols[ni]] : 0.f;
    }
  __syncthreads();

#pragma unroll
  for (int k0 = 0; k0 < HD; k0 += 32) {
    bf16x8 af[4], bfv[4];
#pragma unroll
    for (int mi = 0; mi < 4; mi++)
      af[mi] = *(const bf16x8*)&Qs[wr + mi * 16 + r][k0 + q8];
#pragma unroll
    for (int ni = 0; ni < 4; ni++)
      bfv[ni] = *(const bf16x8*)&Qs[wc + ni * 16 + r][k0 + q8];
#pragma unroll
    for (int mi = 0; mi < 4; mi++)
#pragma unroll
      for (int ni = 0; ni < 4; ni++)
        acc[mi][ni] = __builtin_amdgcn_mfma_f32_16x16x32_bf16(af[mi], bfv[ni],
                                                              acc[mi][ni], 0, 0, 0);
  }

  float mx[4][4];
#pragma unroll
  for (int mi = 0; mi < 4; mi++)
#pragma unroll
    for (int rg = 0; rg < 4; rg++) {
      float m = -1e30f;
#pragma unroll
      for (int ni = 0; ni < 4; ni++)
        if (cv[ni]) m = fmaxf(m, acc[mi][ni][rg]);
#pragma unroll
      for (int o = 1; o < 16; o <<= 1) m = fmaxf(m, __shfl_xor(m, o, 64));
      mx[mi][rg] = m;
    }
  if (r == 0) {
#pragma unroll
    for (int mi = 0; mi < 4; mi++)
#pragma unroll
      for (int rg = 0; rg < 4; rg++)
        redm[wave & 1][wr + mi * 16 + quad * 4 + rg] = mx[mi][rg];
  }
  __syncthreads();

#pragma unroll
  for (int mi = 0; mi < 4; mi++)
#pragma unroll
    for (int rg = 0; rg < 4; rg++) {
      int row = wr + mi * 16 + quad * 4 + rg;
      float rmax = fmaxf(redm[0][row], redm[1][row]);
      float s = 0.f;
#pragma unroll
      for (int ni = 0; ni < 4; ni++) {
        float e = cv[ni] ? __expf(acc[mi][ni][rg] - rmax) : 0.f;
        acc[mi][ni][rg] = e;
        s += e;
      }
#pragma unroll
      for (int o = 1; o < 16; o <<= 1) s += __shfl_xor(s, o, 64);
      if (r == 0) reds[wave & 1][row] = s;
    }
  __syncthreads();

#pragma unroll
  for (int mi = 0; mi < 4; mi++)
#pragma unroll
    for (int rg = 0; rg < 4; rg++) {
      int row = wr + mi * 16 + quad * 4 + rg;
      float inv = 1.0f / (reds[0][row] + reds[1][row]);
#pragma unroll
      for (int ni = 0; ni < 4; ni++)
        Ps[row][cols[ni]] = __float2bfloat16(acc[mi][ni][rg] * inv);
    }
  __syncthreads();

  const int wr2 = (wave >> 1) * 48;
  f32x4 po[3][4] = {};
#pragma unroll
  for (int kk = 0; kk < 128; kk += 32) {
    bf16x8 aq[3], bp[4];
#pragma unroll
    for (int mi = 0; mi < 3; mi++)
      aq[mi] = *(const bf16x8*)&Qt[wr2 + mi * 16 + r][kk + q8];
#pragma unroll
    for (int ni = 0; ni < 4; ni++)
      bp[ni] = *(const bf16x8*)&Ps[wc + ni * 16 + r][kk + q8];
#pragma unroll
    for (int mi = 0; mi < 3; mi++)
#pragma unroll
      for (int ni = 0; ni < 4; ni++)
        po[mi][ni] = __builtin_amdgcn_mfma_f32_16x16x32_bf16(aq[mi], bp[ni],
                                                             po[mi][ni], 0, 0, 0);
  }
#pragma unroll
  for (int mi = 0; mi < 3; mi++)
#pragma unroll
    for (int ni = 0; ni < 4; ni++) {
      int qcol = wc + ni * 16 + r;
      if (qcol < SS) {
        int d0 = wr2 + mi * 16 + quad * 4;
        __hip_bfloat16 hb[4];
#pragma unroll
        for (int rg = 0; rg < 4; rg++) hb[rg] = __float2bfloat16(po[mi][ni][rg]);
        *(short4v*)(out + (size_t)(b * SS + qcol) * DD + h * HD + d0) = *(short4v*)hb;
      }
    }
}

// ---------------- 8-phase-style bf16 MFMA GEMM (BM=256): C = A @ Bt^T ------
// MODE 0: outf = C + bias; MODE 1: outb = gelu(C + bias) bf16; MODE 2: outf = C + bias + resid
// R8 (proven): 256x128 tile, BK=64, 8 waves (4Mx2N), tri-buffered LDS (144KB).
// 2 phases per K-tile, each {8 ds_read_b128 || 3 global_load_lds of tile t+2
// || setprio(1)+16 MFMA+setprio(0) || s_barrier}. vmcnt(6) at K-tile boundary;
// vmcnt(0) only in the final two tiles. Tri-buffer race-free by construction.
// Chunk-XOR swizzle: stored chunk = cp ^ ((row>>1)&7); read applies same key.
template <int MODE>
__launch_bounds__(512, 2)
__global__ void gemm256(const __hip_bfloat16* __restrict__ A,
                        const __hip_bfloat16* __restrict__ Bt,
                        const float* __restrict__ bias,
                        const float* __restrict__ resid,
                        float* __restrict__ outf,
                        __hip_bfloat16* __restrict__ outb,
                        int M, int N, int K) {
  constexpr int BM = 256, BN = 128, BK = 64;
  __shared__ __align__(16) __hip_bfloat16 As[3][BM * BK];  // 96 KB
  __shared__ __align__(16) __hip_bfloat16 Bs[3][BN * BK];  // 48 KB
  const int gm = M >> 8, gn = N >> 7;
  const int nwg = gm * gn;
  // bijective XCD swizzle (m204): contiguous chunk per XCD, any nwg
  int wg = (int)blockIdx.x;
  {
    int qc = nwg >> 3, rc = nwg & 7;
    int xcd = wg & 7, pos = wg >> 3;
    wg = (xcd < rc ? xcd * (qc + 1) : rc * (qc + 1) + (xcd - rc) * qc) + pos;
  }
  const int nt0 = wg / gm, mt = wg - nt0 * gm;   // n-major: same B-panel per chunk
  const int m0 = mt * BM, n0 = nt0 * BN;
  const int tid = threadIdx.x;
  const int wave = tid >> 6, lane = tid & 63;
  const int wm = wave >> 1, wn = wave & 1;       // 4M x 2N wave grid
  const int r = lane & 15, q = lane >> 4;

  // ---- staging source pointers (6 x 16B chunks per thread per K-tile) ----
  const int srow = tid >> 3;                     // 0..63
  const int scp = (tid & 7) ^ ((tid >> 4) & 7);  // cir ^ key(srow), key=(srow>>1)&7
  const __hip_bfloat16* gA0 = A + (size_t)(m0 + srow) * K + scp * 8;
  const __hip_bfloat16* gA1 = A + (size_t)(m0 + srow + 64) * K + scp * 8;
  const __hip_bfloat16* gA2 = A + (size_t)(m0 + srow + 128) * K + scp * 8;
  const __hip_bfloat16* gA3 = A + (size_t)(m0 + srow + 192) * K + scp * 8;
  const __hip_bfloat16* gB0 = Bt + (size_t)(n0 + srow) * K + scp * 8;
  const __hip_bfloat16* gB1 = Bt + (size_t)(n0 + srow + 64) * K + scp * 8;

  // ---- frag read offsets (elements), swizzled chunk per kk ----
  const int kr = (r >> 1) & 7;
  const int c0 = (q ^ kr) * 8;                   // kk=0 chunk
  const int c1 = ((4 + q) ^ kr) * 8;             // kk=1 chunk
  const int aBase = wm * 4096 + r * 64;          // (wm*64 + r) * 64
  const int bBase = wn * 4096 + r * 64;

  f32x4 acc[4][4] = {};

  const int NT = K / BK;
  // prologue: stage tiles 0 and 1
#pragma unroll
  for (int t = 0; t < 2; ++t) {
    const int kel = t * BK;
    async_copy16(&As[t][tid * 8],          gA0 + kel);
    async_copy16(&As[t][(tid + 512) * 8],  gA1 + kel);
    async_copy16(&As[t][(tid + 1024) * 8], gA2 + kel);
    async_copy16(&As[t][(tid + 1536) * 8], gA3 + kel);
    async_copy16(&Bs[t][tid * 8],          gB0 + kel);
    async_copy16(&Bs[t][(tid + 512) * 8],  gB1 + kel);
  }
  asm volatile("s_waitcnt vmcnt(6)" ::: "memory");  // tile 0 resident
  __builtin_amdgcn_s_barrier();
  __builtin_amdgcn_sched_barrier(0);

  int slot = 0;
  for (int t = 0; t < NT; ++t) {
    const int s2 = (slot >= 1) ? slot - 1 : slot + 2;  // (t+2)%3
    const bool st = (t + 2 < NT);
    const int kel = (t + 2) * BK;
    // ---- phase A (kk=0) ----
    {
      bf16x8 af[4], bfr[4];
#pragma unroll
      for (int mi = 0; mi < 4; mi++)
        af[mi] = *(const bf16x8*)(&As[slot][aBase + mi * 1024 + c0]);
#pragma unroll
      for (int ni = 0; ni < 4; ni++)
        bfr[ni] = *(const bf16x8*)(&Bs[slot][bBase + ni * 1024 + c0]);
      if (st) {
        async_copy16(&As[s2][tid * 8],         gA0 + kel);
        async_copy16(&As[s2][(tid + 512) * 8], gA1 + kel);
        async_copy16(&Bs[s2][tid * 8],         gB0 + kel);
      }
      __builtin_amdgcn_s_setprio(1);
#pragma unroll
      for (int mi = 0; mi < 4; mi++)
#pragma unroll
        for (int ni = 0; ni < 4; ni++)
          acc[mi][ni] = __builtin_amdgcn_mfma_f32_16x16x32_bf16(af[mi], bfr[ni],
                                                                acc[mi][ni], 0, 0, 0);
      __builtin_amdgcn_s_setprio(0);
      __builtin_amdgcn_s_barrier();
      __builtin_amdgcn_sched_barrier(0);
    }
    // ---- phase B (kk=1) ----
    {
      bf16x8 af[4], bfr[4];
#pragma unroll
      for (int mi = 0; mi < 4; mi++)
        af[mi] = *(const bf16x8*)(&As[slot][aBase + mi * 1024 + c1]);
#pragma unroll
      for (int ni = 0; ni < 4; ni++)
        bfr[ni] = *(const bf16x8*)(&Bs[slot][bBase + ni * 1024 + c1]);
      if (st) {
        async_copy16(&As[s2][(tid + 1024) * 8], gA2 + kel);
        async_copy16(&As[s2][(tid + 1536) * 8], gA3 + kel);
        async_copy16(&Bs[s2][(tid + 512) * 8],  gB1 + kel);
      }
      __builtin_amdgcn_s_setprio(1);
#pragma unroll
      for (int mi = 0; mi < 4; mi++)
#pragma unroll
        for (int ni = 0; ni < 4; ni++)
          acc[mi][ni] = __builtin_amdgcn_mfma_f32_16x16x32_bf16(af[mi], bfr[ni],
                                                                acc[mi][ni], 0, 0, 0);
      __builtin_amdgcn_s_setprio(0);
      if (st) asm volatile("s_waitcnt vmcnt(6)" ::: "memory");  // t+1 resident
      else    asm volatile("s_waitcnt vmcnt(0)" ::: "memory");  // tail drain
      __builtin_amdgcn_s_barrier();
      __builtin_amdgcn_sched_barrier(0);
    }
    slot = (slot == 2) ? 0 : slot + 1;
  }

  // ---- epilogue ----
#pragma unroll
  for (int mi = 0; mi < 4; mi++) {
#pragma unroll
    for (int ni = 0; ni < 4; ni++) {
      int col = n0 + wn * 64 + ni * 16 + r;
      float bv = bias[col];
#pragma unroll
      for (int rg = 0; rg < 4; rg++) {
        int row = m0 + wm * 64 + mi * 16 + q * 4 + rg;
        size_t oidx = (size_t)row * N + col;
        float v = acc[mi][ni][rg] + bv;
        if constexpr (MODE == 2) v += resid[oidx];
        if constexpr (MODE == 1) {
          v = 0.5f * v * (1.0f + erff(v * 0.70710678118654752f));
          outb[oidx] = __float2bfloat16(v);
        } else {
          outf[oidx] = v;
        }
      }
    }
  }
}

// ---------------- same schedule, BM=64 geometry (R9, for N=768 GEMMs) ------
// 64x128 tile, BK=64, 4 waves (2Mx2N, 32x64/wave), tri-buffer 72KB -> 2
// blocks/CU, grid 600 (was 150 @ BM=256: 106 CUs idle). Same 6 loads/thread/
// K-tile (A:2 + B:4) -> identical vmcnt(6) accounting; same tri-buffer safety;
// same chunk-XOR swizzle (key (row>>1)&7 invariant under +32/+64/+96).
template <int MODE>
__launch_bounds__(256, 2)
__global__ void gemm64(const __hip_bfloat16* __restrict__ A,
                       const __hip_bfloat16* __restrict__ Bt,
                       const float* __restrict__ bias,
                       const float* __restrict__ resid,
                       float* __restrict__ outf,
                       __hip_bfloat16* __restrict__ outb,
                       int M, int N, int K) {
  constexpr int BM = 64, BN = 128, BK = 64;
  __shared__ __align__(16) __hip_bfloat16 As[3][BM * BK];  // 24 KB
  __shared__ __align__(16) __hip_bfloat16 Bs[3][BN * BK];  // 48 KB
  const int gm = M >> 6, gn = N >> 7;
  const int nwg = gm * gn;
  int wg = (int)blockIdx.x;
  {
    int qc = nwg >> 3, rc = nwg & 7;
    int xcd = wg & 7, pos = wg >> 3;
    wg = (xcd < rc ? xcd * (qc + 1) : rc * (qc + 1) + (xcd - rc) * qc) + pos;
  }
  const int nt0 = wg / gm, mt = wg - nt0 * gm;   // n-major: B-panel shared in chunk
  const int m0 = mt * BM, n0 = nt0 * BN;
  const int tid = threadIdx.x;
  const int wave = tid >> 6, lane = tid & 63;
  const int wm = wave >> 1, wn = wave & 1;       // 2M x 2N wave grid
  const int r = lane & 15, q = lane >> 4;

  // staging: A 64 rows x 8 chunks = 512 (2/thr), B 128 rows x 8 = 1024 (4/thr)
  const int srow = tid >> 3;                     // 0..31
  const int scp = (tid & 7) ^ ((tid >> 4) & 7);  // chunk ^ ((row>>1)&7)
  const __hip_bfloat16* gA0 = A + (size_t)(m0 + srow) * K + scp * 8;
  const __hip_bfloat16* gA1 = A + (size_t)(m0 + srow + 32) * K + scp * 8;
  const __hip_bfloat16* gB0 = Bt + (size_t)(n0 + srow) * K + scp * 8;
  const __hip_bfloat16* gB1 = Bt + (size_t)(n0 + srow + 32) * K + scp * 8;
  const __hip_bfloat16* gB2 = Bt + (size_t)(n0 + srow + 64) * K + scp * 8;
  const __hip_bfloat16* gB3 = Bt + (size_t)(n0 + srow + 96) * K + scp * 8;

  const int kr = (r >> 1) & 7;
  const int c0 = (q ^ kr) * 8;
  const int c1 = ((4 + q) ^ kr) * 8;
  const int aBase = wm * 2048 + r * 64;          // (wm*32 + r) * 64
  const int bBase = wn * 4096 + r * 64;

  f32x4 acc[2][4] = {};

  const int NT = K / BK;
  // prologue: stage tiles 0 and 1
#pragma unroll
  for (int t = 0; t < 2; ++t) {
    const int kel = t * BK;
    async_copy16(&As[t][tid * 8],         gA0 + kel);
    async_copy16(&As[t][(tid + 256) * 8], gA1 + kel);
    async_copy16(&Bs[t][tid * 8],         gB0 + kel);
    async_copy16(&Bs[t][(tid + 256) * 8], gB1 + kel);
    async_copy16(&Bs[t][(tid + 512) * 8], gB2 + kel);
    async_copy16(&Bs[t][(tid + 768) * 8], gB3 + kel);
  }
  asm volatile("s_waitcnt vmcnt(6)" ::: "memory");  // tile 0 resident
  __builtin_amdgcn_s_barrier();
  __builtin_amdgcn_sched_barrier(0);

  int slot = 0;
  for (int t = 0; t < NT; ++t) {
    const int s2 = (slot >= 1) ? slot - 1 : slot + 2;  // (t+2)%3
    const bool st = (t + 2 < NT);
    const int kel = (t + 2) * BK;
    // ---- phase A (kk=0) ----
    {
      bf16x8 af[2], bfr[4];
#pragma unroll
      for (int mi = 0; mi < 2; mi++)
        af[mi] = *(const bf16x8*)(&As[slot][aBase + mi * 1024 + c0]);
#pragma unroll
      for (int ni = 0; ni < 4; ni++)
        bfr[ni] = *(const bf16x8*)(&Bs[slot][bBase + ni * 1024 + c0]);
      if (st) {
        async_copy16(&As[s2][tid * 8],         gA0 + kel);
        async_copy16(&As[s2][(tid + 256) * 8], gA1 + kel);
        async_copy16(&Bs[s2][tid * 8],         gB0 + kel);
      }
      __builtin_amdgcn_s_setprio(1);
#pragma unroll
      for (int mi = 0; mi < 2; mi++)
#pragma unroll
        for (int ni = 0; ni < 4; ni++)
          acc[mi][ni] = __builtin_amdgcn_mfma_f32_16x16x32_bf16(af[mi], bfr[ni],
                                                                acc[mi][ni], 0, 0, 0);
      __builtin_amdgcn_s_setprio(0);
      __builtin_amdgcn_s_barrier();
      __builtin_amdgcn_sched_barrier(0);
    }
    // ---- phase B (kk=1) ----
    {
      bf16x8 af[2], bfr[4];
#pragma unroll
      for (int mi = 0; mi < 2; mi++)
        af[mi] = *(const bf16x8*)(&As[slot][aBase + mi * 1024 + c1]);
#pragma unroll
      for (int ni = 0; ni < 4; ni++)
        bfr[ni] = *(const bf16x8*)(&Bs[slot][bBase + ni * 1024 + c1]);
      if (st) {
        async_copy16(&Bs[s2][(tid + 256) * 8], gB1 + kel);
        async_copy16(&Bs[s2][(tid + 512) * 8], gB2 + kel);
        async_copy16(&Bs[s2][(tid + 768) * 8], gB3 + kel);
      }
      __builtin_amdgcn_s_setprio(1);
#pragma unroll
      for (int mi = 0; mi < 2; mi++)
#pragma unroll
        for (int ni = 0; ni < 4; ni++)
          acc[mi][ni] = __builtin_amdgcn_mfma_f32_16x16x32_bf16(af[mi], bfr[ni],
                                                                acc[mi][ni], 0, 0, 0);
      __builtin_amdgcn_s_setprio(0);
      if (st) asm volatile("s_waitcnt vmcnt(6)" ::: "memory");  // t+1 resident
      else    asm volatile("s_waitcnt vmcnt(0)" ::: "memory");  // tail drain
      __builtin_amdgcn_s_barrier();
      __builtin_amdgcn_sched_barrier(0);
    }
    slot = (slot == 2) ? 0 : slot + 1;
  }

  // ---- epilogue ----
#pragma unroll
  for (int mi = 0; mi < 2; mi++) {
#pragma unroll
    for (int ni = 0; ni < 4; ni++) {
      int col = n0 + wn * 64 + ni * 16 + r;
      float bv = bias[col];
#pragma unroll
      for (int rg = 0; rg < 4; rg++) {
        int row = m0 + wm * 32 + mi * 16 + q * 4 + rg;
        size_t oidx = (size_t)row * N + col;
        float v = acc[mi][ni][rg] + bv;
        if constexpr (MODE == 2) v += resid[oidx];
        if constexpr (MODE == 1) {
          v = 0.5f * v * (1.0f + erff(v * 0.70710678118654752f));
          outb[oidx] = __float2bfloat16(v);
        } else {
          outf[oidx] = v;
        }
      }
    }
  }
}

// ---------------- split-K classifier ----------------
#define CCHUNK 3072
#define NCHUNK 25   // 76800 / 3072
__global__ void classifier_part(const float* __restrict__ x,
                                const float* __restrict__ Wfc,
                                float* __restrict__ part) {
  int chunk = blockIdx.x, b = blockIdx.y, tid = threadIdx.x;
  const float* xb = x + (size_t)b * (SS * DD) + chunk * CCHUNK;
  const float* w = Wfc + 2 * (size_t)chunk * CCHUNK;
  float a0 = 0.f, a1 = 0.f;
  for (int i = tid; i < CCHUNK; i += 256) {
    float xv = xb[i];
    float2 wv = *(const float2*)(w + 2 * i);
    a0 += xv * wv.x;
    a1 += xv * wv.y;
  }
  __shared__ float sbuf[4];
  a0 = block_sum256(a0, sbuf);
  a1 = block_sum256(a1, sbuf);
  if (tid == 0) {
    part[(b * NCHUNK + chunk) * 2] = a0;
    part[(b * NCHUNK + chunk) * 2 + 1] = a1;
  }
}

__global__ void classifier_final(const float* __restrict__ part,
                                 const float* __restrict__ bfc,
                                 float* __restrict__ out) {
  int b = threadIdx.x;  // 64 threads
  float a0 = bfc[0], a1 = bfc[1];
#pragma unroll
  for (int c = 0; c < NCHUNK; c++) {
    a0 += part[(b * NCHUNK + c) * 2];
    a1 += part[(b * NCHUNK + c) * 2 + 1];
  }
  out[2 * b] = a0;
  out[2 * b + 1] = a1;
}

// ---------------- launcher ----------------
extern "C" void kernel_launch(void* const* d_in, const int* in_sizes, int n_in,
                              void* d_out, int out_size, void* d_ws, size_t ws_size,
                              hipStream_t stream) {
  const float* Tmpl = (const float*)d_in[0];
  const float* Pseq = (const float*)d_in[1];
  const float* Wc   = (const float*)d_in[2];
  const float* bc   = (const float*)d_in[3];
  const float* gp   = (const float*)d_in[4];
  const float* bp   = (const float*)d_in[5];
  const float* W1   = (const float*)d_in[6];
  const float* b1   = (const float*)d_in[7];
  const float* W2   = (const float*)d_in[8];
  const float* b2   = (const float*)d_in[9];
  const float* g1   = (const float*)d_in[10];
  const float* bn1  = (const float*)d_in[11];
  const float* g2   = (const float*)d_in[12];
  const float* bn2  = (const float*)d_in[13];
  const float* Wfc  = (const float*)d_in[14];
  const float* bfc  = (const float*)d_in[15];
  float* out = (float*)d_out;
  (void)in_sizes; (void)n_in; (void)out_size; (void)ws_size;

  char* ws = (char*)d_ws;
  size_t off = 0;
  auto alloc = [&](size_t n) { size_t o = off; off += (n + 255) & ~(size_t)255; return o; };

  __hip_bfloat16* Wct = (__hip_bfloat16*)(ws + alloc((size_t)768 * 768 * 2));
  __hip_bfloat16* W1t = (__hip_bfloat16*)(ws + alloc((size_t)768 * 3072 * 2));
  __hip_bfloat16* W2t = (__hip_bfloat16*)(ws + alloc((size_t)3072 * 768 * 2));
  size_t h1_off = alloc((size_t)ROWS * FF_ * 2);
  __hip_bfloat16* h1 = (__hip_bfloat16*)(ws + h1_off);
  float* param_enc = (float*)(ws + h1_off);            // alias: dead before h1 live
  size_t slb_off = alloc((size_t)ROWS * DD * 2);
  __hip_bfloat16* src_ln_bf = (__hip_bfloat16*)(ws + slb_off);
  __hip_bfloat16* pooled = (__hip_bfloat16*)(ws + slb_off);  // alias
  size_t ao_off = alloc((size_t)ROWS * DD * 4);
  __hip_bfloat16* attn_out_b = (__hip_bfloat16*)(ws + ao_off);
  float* pe_lin = (float*)(ws + ao_off);               // alias
  float* pbias = (float*)(ws + alloc((size_t)512 * SS * SS * 4));
  float* src = (float*)(ws + alloc((size_t)ROWS * DD * 4));
  float* src_ln = (float*)(ws + alloc((size_t)ROWS * DD * 4));
  float* z = (float*)(ws + alloc((size_t)ROWS * DD * 4));
  float* cpart = (float*)(ws + alloc((size_t)BB * NCHUNK * 2 * 4));

  // ---- layer-invariant precompute ----
  convert_transpose<<<dim3(768 / 32, 768 / 32), 256, 0, stream>>>(Wc, Wct, 768, 768);
  convert_transpose<<<dim3(3072 / 32, 768 / 32), 256, 0, stream>>>(W1, W1t, 768, 3072);
  convert_transpose<<<dim3(768 / 32, 3072 / 32), 256, 0, stream>>>(W2, W2t, 3072, 768);
  pool_mean<<<ROWS * DD / 256, 256, 0, stream>>>(Pseq, pooled);
  gemm64<0><<<(DD / 128) * (ROWS / 64), 256, 0, stream>>>(
      pooled, Wct, bc, nullptr, pe_lin, nullptr, ROWS, DD, 768);
  ln_row<false, false, false><<<ROWS, 192, 0, stream>>>(
      pe_lin, nullptr, nullptr, gp, bp, param_enc, nullptr);
  param_bias_mfma<<<512, 256, 0, stream>>>(param_enc, pbias);
  add_pe<<<ROWS * DD / 256, 256, 0, stream>>>(Tmpl, src);

  // ---- 4 shared layers ----
  for (int l = 0; l < 4; ++l) {
    attn_fused_mfma<<<512, 256, 0, stream>>>(src, pbias, attn_out_b);
    ln_row<true, true, true><<<ROWS, 192, 0, stream>>>(
        nullptr, attn_out_b, src, g1, bn1, src_ln, src_ln_bf);
    gemm256<1><<<(FF_ / 128) * (ROWS / 256), 512, 0, stream>>>(
        src_ln_bf, W1t, b1, nullptr, nullptr, h1, ROWS, FF_, DD);
    gemm64<2><<<(DD / 128) * (ROWS / 64), 256, 0, stream>>>(
        h1, W2t, b2, src_ln, z, nullptr, ROWS, DD, FF_);
    ln_row<false, false, false><<<ROWS, 192, 0, stream>>>(
        z, nullptr, nullptr, g2, bn2, src, nullptr);
  }

  classifier_part<<<dim3(NCHUNK, BB), 256, 0, stream>>>(src, Wfc, cpart);
  classifier_final<<<1, 64, 0, stream>>>(cpart, bfc, out);
}

// Round 6
// 978.016 us; speedup vs baseline: 1.1325x; 1.1325x over previous
//
#include <hip/hip_runtime.h>
#include <hip/hip_bf16.h>
#include <math.h>

// Model: B=64,S=100,D=768,H=8,P=8,FF=3072,HD=96, 4 shared layers.
//  - param path computed ONCE (layer-shared); param_bias via MFMA (R4).
//  - GEMM gemm256 (R10): R8's proven fine-interleaved schedule with BK=64->32
//    so LDS = 3 x 24KB = 72KB -> 2 blocks/CU (16 waves/CU). R8/R9 occupancy
//    counters proved every config was round-quantized at 1 blk/CU (19.3% =
//    3 rounds for 2.34 rounds of work on grid 600). Per K-tile: one phase
//    {8 ds_read_b128 || 3 global_load_lds of tile t+2 || setprio+16 MFMA},
//    boundary vmcnt(3) counted (FIFO: tile t+1's 3 loads guaranteed done),
//    one barrier/tile. Tri-buffer race-free: slot (t+2)%3 last read in tile
//    t-1, >=1 barrier before any t+2 load issues. BK=32 chunk-XOR swizzle
//    (R5-proven, 0 conflicts): stored chunk c = global chunk c^((row>>1)&3);
//    read XORs same key. Bijective XCD swizzle (m204), n-major.
//    gemm64 deleted (R9 regression: re-created quantization + rule#19).
//  - attention per (b,h): MFMA scores (pbias C-init) + reg-softmax + MFMA PV.
//  - split-K classifier + float4-vectorized LayerNorm.

typedef __attribute__((ext_vector_type(8))) short bf16x8;
typedef __attribute__((ext_vector_type(4))) float f32x4;
typedef __attribute__((ext_vector_type(4))) short short4v;

#define BB 64
#define SS 100
#define DD 768
#define HH 8
#define HD 96
#define FF_ 3072
#define ROWS 6400           // B*S
#define LN10000 9.210340371976184f

__device__ __forceinline__ void async_copy16(void* lds_dst, const void* gsrc) {
  __builtin_amdgcn_global_load_lds(
      (const __attribute__((address_space(1))) void*)gsrc,
      (__attribute__((address_space(3))) void*)lds_dst, 16, 0, 0);
}

// ---------------- block-wide sums ----------------
__device__ __forceinline__ float block_sum256(float v, float* sbuf) {
#pragma unroll
  for (int o = 32; o > 0; o >>= 1) v += __shfl_xor(v, o, 64);
  int tid = threadIdx.x;
  __syncthreads();
  if ((tid & 63) == 0) sbuf[tid >> 6] = v;
  __syncthreads();
  return sbuf[0] + sbuf[1] + sbuf[2] + sbuf[3];
}

__device__ __forceinline__ float block_sum192(float v, float* sbuf) {
#pragma unroll
  for (int o = 32; o > 0; o >>= 1) v += __shfl_xor(v, o, 64);
  int tid = threadIdx.x;
  __syncthreads();
  if ((tid & 63) == 0) sbuf[tid >> 6] = v;
  __syncthreads();
  return sbuf[0] + sbuf[1] + sbuf[2];
}

// ---------------- fp32 [K,N] -> bf16 [N,K] transpose-convert ----------------
__global__ void convert_transpose(const float* __restrict__ in,
                                  __hip_bfloat16* __restrict__ out,
                                  int K, int N) {
  __shared__ float t[32][33];
  int n0 = blockIdx.x * 32, k0 = blockIdx.y * 32;
  int tid = threadIdx.x;
  int tx = tid & 31, ty = tid >> 5;  // ty 0..7
#pragma unroll
  for (int j = 0; j < 32; j += 8)
    t[ty + j][tx] = in[(size_t)(k0 + ty + j) * N + n0 + tx];
  __syncthreads();
#pragma unroll
  for (int j = 0; j < 32; j += 8)
    out[(size_t)(n0 + ty + j) * K + k0 + tx] = __float2bfloat16(t[tx][ty + j]);
}

// ---------------- pooled = mean_P(param_seq) -> bf16 ----------------
__global__ void pool_mean(const float* __restrict__ ps,
                          __hip_bfloat16* __restrict__ pooled) {
  int idx = blockIdx.x * 256 + threadIdx.x;  // < 6400*768
  int row = idx / DD, c = idx - row * DD;
  float s = 0.f;
#pragma unroll
  for (int p = 0; p < 8; p++) s += ps[(size_t)(row * 8 + p) * DD + c];
  pooled[idx] = __float2bfloat16(s * 0.125f);
}

// ---------------- src = template + PE ----------------
__global__ void add_pe(const float* __restrict__ t, float* __restrict__ src) {
  int idx = blockIdx.x * 256 + threadIdx.x;
  int row = idx / DD, c = idx - row * DD;
  int srow = row % SS;
  int c2 = c & ~1;
  float ang = (float)srow * expf((float)c2 * (-LN10000 / (float)DD));
  float pe = (c & 1) ? cosf(ang) : sinf(ang);
  src[idx] = t[idx] + pe;
}

// ---------------- LayerNorm over rows of 768 (192 thr, float4) ----------------
// XB16: X is bf16; RESID: add R (fp32); WB16: also write bf16 copy
template <bool XB16, bool RESID, bool WB16>
__global__ void ln_row(const float* __restrict__ Xf,
                       const __hip_bfloat16* __restrict__ Xb,
                       const float* __restrict__ R,
                       const float* __restrict__ g, const float* __restrict__ bb,
                       float* __restrict__ of, __hip_bfloat16* __restrict__ ob) {
  int row = blockIdx.x, tid = threadIdx.x;
  size_t base = (size_t)row * DD;
  int c4 = tid * 4;
  float4 v;
  if constexpr (XB16) {
    short4v xv = *(const short4v*)(Xb + base + c4);
    __hip_bfloat16* p = (__hip_bfloat16*)&xv;
    v.x = __bfloat162float(p[0]); v.y = __bfloat162float(p[1]);
    v.z = __bfloat162float(p[2]); v.w = __bfloat162float(p[3]);
  } else {
    v = *(const float4*)(Xf + base + c4);
  }
  if (RESID) {
    float4 rv = *(const float4*)(R + base + c4);
    v.x += rv.x; v.y += rv.y; v.z += rv.z; v.w += rv.w;
  }
  __shared__ float sbuf[3];
  float s = block_sum192(v.x + v.y + v.z + v.w, sbuf);
  float mean = s * (1.0f / DD);
  float dx = v.x - mean, dy = v.y - mean, dz = v.z - mean, dw = v.w - mean;
  float ss = block_sum192(dx * dx + dy * dy + dz * dz + dw * dw, sbuf);
  float rs = rsqrtf(ss * (1.0f / DD) + 1e-5f);
  float4 gv = *(const float4*)(g + c4);
  float4 bv = *(const float4*)(bb + c4);
  float4 y;
  y.x = dx * rs * gv.x + bv.x;
  y.y = dy * rs * gv.y + bv.y;
  y.z = dz * rs * gv.z + bv.z;
  y.w = dw * rs * gv.w + bv.w;
  *(float4*)(of + base + c4) = y;
  if (WB16) {
    __hip_bfloat16 hb[4] = {__float2bfloat16(y.x), __float2bfloat16(y.y),
                            __float2bfloat16(y.z), __float2bfloat16(y.w)};
    *(short4v*)(ob + base + c4) = *(short4v*)hb;
  }
}

// ---------------- param_bias via MFMA: pb.pb^T / sqrt(HD) ----------------
__launch_bounds__(256, 2)
__global__ void param_bias_mfma(const float* __restrict__ penc,
                                float* __restrict__ pbias) {
  __shared__ __align__(16) __hip_bfloat16 Qs[128][104];
  const int bh = blockIdx.x;
  const int b = bh >> 3, h = bh & 7;
  const int tid = threadIdx.x;
  const int wave = tid >> 6, lane = tid & 63;
  const int r = lane & 15, quad = lane >> 4;
  const int q8 = quad * 8;
  const int wr = (wave >> 1) * 64, wc = (wave & 1) * 64;
  const float sroot = rsqrtf(9.79795897113f);  // 96^(-1/4)
  for (int i = tid; i < 128 * HD; i += 256) {
    int s = i / HD, d = i - s * HD;
    float v = (s < SS) ? penc[(size_t)(b * SS + s) * DD + h * HD + d] : 0.f;
    Qs[s][d] = __float2bfloat16(v * sroot);
  }
  __syncthreads();
  f32x4 acc[4][4] = {};
#pragma unroll
  for (int k0 = 0; k0 < HD; k0 += 32) {
    bf16x8 af[4], bfv[4];
#pragma unroll
    for (int mi = 0; mi < 4; mi++)
      af[mi] = *(const bf16x8*)&Qs[wr + mi * 16 + r][k0 + q8];
#pragma unroll
    for (int ni = 0; ni < 4; ni++)
      bfv[ni] = *(const bf16x8*)&Qs[wc + ni * 16 + r][k0 + q8];
#pragma unroll
    for (int mi = 0; mi < 4; mi++)
#pragma unroll
      for (int ni = 0; ni < 4; ni++)
        acc[mi][ni] = __builtin_amdgcn_mfma_f32_16x16x32_bf16(af[mi], bfv[ni],
                                                              acc[mi][ni], 0, 0, 0);
  }
  float* pb = pbias + (size_t)bh * SS * SS;
#pragma unroll
  for (int mi = 0; mi < 4; mi++)
#pragma unroll
    for (int ni = 0; ni < 4; ni++) {
      int col = wc + ni * 16 + r;
      if (col < SS) {
#pragma unroll
        for (int rg = 0; rg < 4; rg++) {
          int row = wr + mi * 16 + quad * 4 + rg;
          if (row < SS) pb[row * SS + col] = acc[mi][ni][rg];
        }
      }
    }
}

// ---------------- fused MFMA attention per (b,h) ----------------
__launch_bounds__(256, 2)
__global__ void attn_fused_mfma(const float* __restrict__ src,
                                const float* __restrict__ pbias,
                                __hip_bfloat16* __restrict__ out) {
  __shared__ __align__(16) char umem[128 * 136 * 2];  // Qs[128][104] then Ps[128][136]
  __shared__ __align__(16) __hip_bfloat16 Qt[96][136];
  __shared__ float redm[2][128];
  __shared__ float reds[2][128];
  __hip_bfloat16 (*Qs)[104] = (__hip_bfloat16 (*)[104])umem;
  __hip_bfloat16 (*Ps)[136] = (__hip_bfloat16 (*)[136])umem;

  const int bh = blockIdx.x;
  const int b = bh >> 3, h = bh & 7;
  const int tid = threadIdx.x;
  const int wave = tid >> 6, lane = tid & 63;
  const int r = lane & 15, quad = lane >> 4;
  const int q8 = quad * 8;
  const int wr = (wave >> 1) * 64, wc = (wave & 1) * 64;

  const float sroot = rsqrtf(9.79795897113f);  // 96^(-1/4)
  for (int i = tid; i < SS * HD; i += 256) {
    int s = i / HD, d = i - s * HD;
    float v = src[(size_t)(b * SS + s) * DD + h * HD + d];
    Qs[s][d] = __float2bfloat16(v * sroot);
    Qt[d][s] = __float2bfloat16(v);
  }
  for (int i = tid; i < 28 * HD; i += 256) {  // zero pads
    int s = i / HD, d = i - s * HD;           // s in 0..27
    Qs[100 + s][d] = __float2bfloat16(0.f);
    Qt[d][100 + s] = __float2bfloat16(0.f);
  }

  const float* pb = pbias + (size_t)bh * SS * SS;
  bool cv[4]; int cols[4];
#pragma unroll
  for (int ni = 0; ni < 4; ni++) { cols[ni] = wc + ni * 16 + r; cv[ni] = cols[ni] < SS; }
  f32x4 acc[4][4];
#pragma unroll
  for (int mi = 0; mi < 4; mi++)
#pragma unroll
    for (int rg = 0; rg < 4; rg++) {
      int row = wr + mi * 16 + quad * 4 + rg;
#pragma unroll
      for (int ni = 0; ni < 4; ni++)
        acc[mi][ni][rg] = (row < SS && cv[ni]) ? pb[row * SS + cols[ni]] : 0.f;
    }
  __syncthreads();

#pragma unroll
  for (int k0 = 0; k0 < HD; k0 += 32) {
    bf16x8 af[4], bfv[4];
#pragma unroll
    for (int mi = 0; mi < 4; mi++)
      af[mi] = *(const bf16x8*)&Qs[wr + mi * 16 + r][k0 + q8];
#pragma unroll
    for (int ni = 0; ni < 4; ni++)
      bfv[ni] = *(const bf16x8*)&Qs[wc + ni * 16 + r][k0 + q8];
#pragma unroll
    for (int mi = 0; mi < 4; mi++)
#pragma unroll
      for (int ni = 0; ni < 4; ni++)
        acc[mi][ni] = __builtin_amdgcn_mfma_f32_16x16x32_bf16(af[mi], bfv[ni],
                                                              acc[mi][ni], 0, 0, 0);
  }

  float mx[4][4];
#pragma unroll
  for (int mi = 0; mi < 4; mi++)
#pragma unroll
    for (int rg = 0; rg < 4; rg++) {
      float m = -1e30f;
#pragma unroll
      for (int ni = 0; ni < 4; ni++)
        if (cv[ni]) m = fmaxf(m, acc[mi][ni][rg]);
#pragma unroll
      for (int o = 1; o < 16; o <<= 1) m = fmaxf(m, __shfl_xor(m, o, 64));
      mx[mi][rg] = m;
    }
  if (r == 0) {
#pragma unroll
    for (int mi = 0; mi < 4; mi++)
#pragma unroll
      for (int rg = 0; rg < 4; rg++)
        redm[wave & 1][wr + mi * 16 + quad * 4 + rg] = mx[mi][rg];
  }
  __syncthreads();

#pragma unroll
  for (int mi = 0; mi < 4; mi++)
#pragma unroll
    for (int rg = 0; rg < 4; rg++) {
      int row = wr + mi * 16 + quad * 4 + rg;
      float rmax = fmaxf(redm[0][row], redm[1][row]);
      float s = 0.f;
#pragma unroll
      for (int ni = 0; ni < 4; ni++) {
        float e = cv[ni] ? __expf(acc[mi][ni][rg] - rmax) : 0.f;
        acc[mi][ni][rg] = e;
        s += e;
      }
#pragma unroll
      for (int o = 1; o < 16; o <<= 1) s += __shfl_xor(s, o, 64);
      if (r == 0) reds[wave & 1][row] = s;
    }
  __syncthreads();

#pragma unroll
  for (int mi = 0; mi < 4; mi++)
#pragma unroll
    for (int rg = 0; rg < 4; rg++) {
      int row = wr + mi * 16 + quad * 4 + rg;
      float inv = 1.0f / (reds[0][row] + reds[1][row]);
#pragma unroll
      for (int ni = 0; ni < 4; ni++)
        Ps[row][cols[ni]] = __float2bfloat16(acc[mi][ni][rg] * inv);
    }
  __syncthreads();

  const int wr2 = (wave >> 1) * 48;
  f32x4 po[3][4] = {};
#pragma unroll
  for (int kk = 0; kk < 128; kk += 32) {
    bf16x8 aq[3], bp[4];
#pragma unroll
    for (int mi = 0; mi < 3; mi++)
      aq[mi] = *(const bf16x8*)&Qt[wr2 + mi * 16 + r][kk + q8];
#pragma unroll
    for (int ni = 0; ni < 4; ni++)
      bp[ni] = *(const bf16x8*)&Ps[wc + ni * 16 + r][kk + q8];
#pragma unroll
    for (int mi = 0; mi < 3; mi++)
#pragma unroll
      for (int ni = 0; ni < 4; ni++)
        po[mi][ni] = __builtin_amdgcn_mfma_f32_16x16x32_bf16(aq[mi], bp[ni],
                                                             po[mi][ni], 0, 0, 0);
  }
#pragma unroll
  for (int mi = 0; mi < 3; mi++)
#pragma unroll
    for (int ni = 0; ni < 4; ni++) {
      int qcol = wc + ni * 16 + r;
      if (qcol < SS) {
        int d0 = wr2 + mi * 16 + quad * 4;
        __hip_bfloat16 hb[4];
#pragma unroll
        for (int rg = 0; rg < 4; rg++) hb[rg] = __float2bfloat16(po[mi][ni][rg]);
        *(short4v*)(out + (size_t)(b * SS + qcol) * DD + h * HD + d0) = *(short4v*)hb;
      }
    }
}

// ---------------- bf16 MFMA GEMM (R10): C[M,N] = A[M,K] @ Bt[N,K]^T --------
// MODE 0: outf = C + bias; MODE 1: outb = gelu(C + bias) bf16; MODE 2: outf = C + bias + resid
// 256x128 tile, BK=32, 8 waves (4Mx2N), tri-buffered LDS 72KB -> 2 blocks/CU.
// Per K-tile (one phase): {8 ds_read_b128 || 3 global_load_lds of tile t+2 ||
// setprio(1)+16 MFMA+setprio(0) || vmcnt(3); s_barrier; sched_barrier}.
// FIFO vmcnt(3): tile t+1's 3 loads (oldest) complete; t+2's 3 stay in flight.
// Tri-buffer: slot (t+2)%3 last read during tile t-1 (barrier-separated).
// BK=32 chunk-XOR swizzle (R5-proven, 0 conflicts): dest chunk c holds global
// chunk c ^ ((row>>1)&3); read XORs same key.
template <int MODE>
__launch_bounds__(512, 4)
__global__ void gemm256(const __hip_bfloat16* __restrict__ A,
                        const __hip_bfloat16* __restrict__ Bt,
                        const float* __restrict__ bias,
                        const float* __restrict__ resid,
                        float* __restrict__ outf,
                        __hip_bfloat16* __restrict__ outb,
                        int M, int N, int K) {
  constexpr int BM = 256, BN = 128, BK = 32;
  __shared__ __align__(16) __hip_bfloat16 As[3][BM * BK];  // 48 KB
  __shared__ __align__(16) __hip_bfloat16 Bs[3][BN * BK];  // 24 KB
  const int gm = M >> 8, gn = N >> 7;
  const int nwg = gm * gn;
  // bijective XCD swizzle (m204): contiguous chunk per XCD, any nwg
  int wg = (int)blockIdx.x;
  {
    int qc = nwg >> 3, rc = nwg & 7;
    int xcd = wg & 7, pos = wg >> 3;
    wg = (xcd < rc ? xcd * (qc + 1) : rc * (qc + 1) + (xcd - rc) * qc) + pos;
  }
  const int nt0 = wg / gm, mt = wg - nt0 * gm;   // n-major: same B-panel per chunk
  const int m0 = mt * BM, n0 = nt0 * BN;
  const int tid = threadIdx.x;
  const int wave = tid >> 6, lane = tid & 63;
  const int wm = wave >> 1, wn = wave & 1;       // 4M x 2N wave grid
  const int r = lane & 15, q = lane >> 4;        // q in 0..3 = 16B chunk of BK=32

  // ---- staging: 3 x 16B chunks per thread per K-tile (A:2, B:1) ----
  const int srow = tid >> 2;                     // 0..127
  const int scp = (tid & 3) ^ ((srow >> 1) & 3); // swizzled source chunk
  const __hip_bfloat16* gA0 = A + (size_t)(m0 + srow) * K + scp * 8;
  const __hip_bfloat16* gA1 = A + (size_t)(m0 + srow + 128) * K + scp * 8;  // key invariant under +128
  const __hip_bfloat16* gB0 = Bt + (size_t)(n0 + srow) * K + scp * 8;

  // ---- frag read offsets (elements) ----
  const int key8 = ((r >> 1) & 3) * 8;
  const int cq = (q * 8) ^ key8;                 // swizzled chunk for this lane
  const int aBase = wm * 2048 + r * 32;          // (wm*64 + r) * 32
  const int bBase = wn * 2048 + r * 32;

  f32x4 acc[4][4] = {};

  const int NT = K / BK;
  // prologue: stage tiles 0 and 1
#pragma unroll
  for (int t = 0; t < 2; ++t) {
    const int kel = t * BK;
    async_copy16(&As[t][tid * 8],          gA0 + kel);
    async_copy16(&As[t][(tid + 512) * 8],  gA1 + kel);
    async_copy16(&Bs[t][tid * 8],          gB0 + kel);
  }
  asm volatile("s_waitcnt vmcnt(3)" ::: "memory");  // tile 0 resident
  __builtin_amdgcn_s_barrier();
  __builtin_amdgcn_sched_barrier(0);

  int slot = 0;
  for (int t = 0; t < NT; ++t) {
    const int s2 = (slot >= 1) ? slot - 1 : slot + 2;  // (t+2)%3
    const bool st = (t + 2 < NT);
    const int kel = (t + 2) * BK;
    bf16x8 af[4], bfr[4];
#pragma unroll
    for (int mi = 0; mi < 4; mi++)
      af[mi] = *(const bf16x8*)(&As[slot][aBase + mi * 512 + cq]);
#pragma unroll
    for (int ni = 0; ni < 4; ni++)
      bfr[ni] = *(const bf16x8*)(&Bs[slot][bBase + ni * 512 + cq]);
    if (st) {
      async_copy16(&As[s2][tid * 8],         gA0 + kel);
      async_copy16(&As[s2][(tid + 512) * 8], gA1 + kel);
      async_copy16(&Bs[s2][tid * 8],         gB0 + kel);
    }
    __builtin_amdgcn_s_setprio(1);
#pragma unroll
    for (int mi = 0; mi < 4; mi++)
#pragma unroll
      for (int ni = 0; ni < 4; ni++)
        acc[mi][ni] = __builtin_amdgcn_mfma_f32_16x16x32_bf16(af[mi], bfr[ni],
                                                              acc[mi][ni], 0, 0, 0);
    __builtin_amdgcn_s_setprio(0);
    if (st) asm volatile("s_waitcnt vmcnt(3)" ::: "memory");  // t+1 resident
    else    asm volatile("s_waitcnt vmcnt(0)" ::: "memory");  // tail drain
    __builtin_amdgcn_s_barrier();
    __builtin_amdgcn_sched_barrier(0);
    slot = (slot == 2) ? 0 : slot + 1;
  }

  // ---- epilogue ----
#pragma unroll
  for (int mi = 0; mi < 4; mi++) {
#pragma unroll
    for (int ni = 0; ni < 4; ni++) {
      int col = n0 + wn * 64 + ni * 16 + r;
      float bv = bias[col];
#pragma unroll
      for (int rg = 0; rg < 4; rg++) {
        int row = m0 + wm * 64 + mi * 16 + q * 4 + rg;
        size_t oidx = (size_t)row * N + col;
        float v = acc[mi][ni][rg] + bv;
        if constexpr (MODE == 2) v += resid[oidx];
        if constexpr (MODE == 1) {
          v = 0.5f * v * (1.0f + erff(v * 0.70710678118654752f));
          outb[oidx] = __float2bfloat16(v);
        } else {
          outf[oidx] = v;
        }
      }
    }
  }
}

// ---------------- split-K classifier ----------------
#define CCHUNK 3072
#define NCHUNK 25   // 76800 / 3072
__global__ void classifier_part(const float* __restrict__ x,
                                const float* __restrict__ Wfc,
                                float* __restrict__ part) {
  int chunk = blockIdx.x, b = blockIdx.y, tid = threadIdx.x;
  const float* xb = x + (size_t)b * (SS * DD) + chunk * CCHUNK;
  const float* w = Wfc + 2 * (size_t)chunk * CCHUNK;
  float a0 = 0.f, a1 = 0.f;
  for (int i = tid; i < CCHUNK; i += 256) {
    float xv = xb[i];
    float2 wv = *(const float2*)(w + 2 * i);
    a0 += xv * wv.x;
    a1 += xv * wv.y;
  }
  __shared__ float sbuf[4];
  a0 = block_sum256(a0, sbuf);
  a1 = block_sum256(a1, sbuf);
  if (tid == 0) {
    part[(b * NCHUNK + chunk) * 2] = a0;
    part[(b * NCHUNK + chunk) * 2 + 1] = a1;
  }
}

__global__ void classifier_final(const float* __restrict__ part,
                                 const float* __restrict__ bfc,
                                 float* __restrict__ out) {
  int b = threadIdx.x;  // 64 threads
  float a0 = bfc[0], a1 = bfc[1];
#pragma unroll
  for (int c = 0; c < NCHUNK; c++) {
    a0 += part[(b * NCHUNK + c) * 2];
    a1 += part[(b * NCHUNK + c) * 2 + 1];
  }
  out[2 * b] = a0;
  out[2 * b + 1] = a1;
}

// ---------------- launcher ----------------
extern "C" void kernel_launch(void* const* d_in, const int* in_sizes, int n_in,
                              void* d_out, int out_size, void* d_ws, size_t ws_size,
                              hipStream_t stream) {
  const float* Tmpl = (const float*)d_in[0];
  const float* Pseq = (const float*)d_in[1];
  const float* Wc   = (const float*)d_in[2];
  const float* bc   = (const float*)d_in[3];
  const float* gp   = (const float*)d_in[4];
  const float* bp   = (const float*)d_in[5];
  const float* W1   = (const float*)d_in[6];
  const float* b1   = (const float*)d_in[7];
  const float* W2   = (const float*)d_in[8];
  const float* b2   = (const float*)d_in[9];
  const float* g1   = (const float*)d_in[10];
  const float* bn1  = (const float*)d_in[11];
  const float* g2   = (const float*)d_in[12];
  const float* bn2  = (const float*)d_in[13];
  const float* Wfc  = (const float*)d_in[14];
  const float* bfc  = (const float*)d_in[15];
  float* out = (float*)d_out;
  (void)in_sizes; (void)n_in; (void)out_size; (void)ws_size;

  char* ws = (char*)d_ws;
  size_t off = 0;
  auto alloc = [&](size_t n) { size_t o = off; off += (n + 255) & ~(size_t)255; return o; };

  __hip_bfloat16* Wct = (__hip_bfloat16*)(ws + alloc((size_t)768 * 768 * 2));
  __hip_bfloat16* W1t = (__hip_bfloat16*)(ws + alloc((size_t)768 * 3072 * 2));
  __hip_bfloat16* W2t = (__hip_bfloat16*)(ws + alloc((size_t)3072 * 768 * 2));
  size_t h1_off = alloc((size_t)ROWS * FF_ * 2);
  __hip_bfloat16* h1 = (__hip_bfloat16*)(ws + h1_off);
  float* param_enc = (float*)(ws + h1_off);            // alias: dead before h1 live
  size_t slb_off = alloc((size_t)ROWS * DD * 2);
  __hip_bfloat16* src_ln_bf = (__hip_bfloat16*)(ws + slb_off);
  __hip_bfloat16* pooled = (__hip_bfloat16*)(ws + slb_off);  // alias
  size_t ao_off = alloc((size_t)ROWS * DD * 4);
  __hip_bfloat16* attn_out_b = (__hip_bfloat16*)(ws + ao_off);
  float* pe_lin = (float*)(ws + ao_off);               // alias
  float* pbias = (float*)(ws + alloc((size_t)512 * SS * SS * 4));
  float* src = (float*)(ws + alloc((size_t)ROWS * DD * 4));
  float* src_ln = (float*)(ws + alloc((size_t)ROWS * DD * 4));
  float* z = (float*)(ws + alloc((size_t)ROWS * DD * 4));
  float* cpart = (float*)(ws + alloc((size_t)BB * NCHUNK * 2 * 4));

  // ---- layer-invariant precompute ----
  convert_transpose<<<dim3(768 / 32, 768 / 32), 256, 0, stream>>>(Wc, Wct, 768, 768);
  convert_transpose<<<dim3(3072 / 32, 768 / 32), 256, 0, stream>>>(W1, W1t, 768, 3072);
  convert_transpose<<<dim3(768 / 32, 3072 / 32), 256, 0, stream>>>(W2, W2t, 3072, 768);
  pool_mean<<<ROWS * DD / 256, 256, 0, stream>>>(Pseq, pooled);
  gemm256<0><<<(DD / 128) * (ROWS / 256), 512, 0, stream>>>(
      pooled, Wct, bc, nullptr, pe_lin, nullptr, ROWS, DD, 768);
  ln_row<false, false, false><<<ROWS, 192, 0, stream>>>(
      pe_lin, nullptr, nullptr, gp, bp, param_enc, nullptr);
  param_bias_mfma<<<512, 256, 0, stream>>>(param_enc, pbias);
  add_pe<<<ROWS * DD / 256, 256, 0, stream>>>(Tmpl, src);

  // ---- 4 shared layers ----
  for (int l = 0; l < 4; ++l) {
    attn_fused_mfma<<<512, 256, 0, stream>>>(src, pbias, attn_out_b);
    ln_row<true, true, true><<<ROWS, 192, 0, stream>>>(
        nullptr, attn_out_b, src, g1, bn1, src_ln, src_ln_bf);
    gemm256<1><<<(FF_ / 128) * (ROWS / 256), 512, 0, stream>>>(
        src_ln_bf, W1t, b1, nullptr, nullptr, h1, ROWS, FF_, DD);
    gemm256<2><<<(DD / 128) * (ROWS / 256), 512, 0, stream>>>(
        h1, W2t, b2, src_ln, z, nullptr, ROWS, DD, FF_);
    ln_row<false, false, false><<<ROWS, 192, 0, stream>>>(
        z, nullptr, nullptr, g2, bn2, src, nullptr);
  }

  classifier_part<<<dim3(NCHUNK, BB), 256, 0, stream>>>(src, Wfc, cpart);
  classifier_final<<<1, 64, 0, stream>>>(cpart, bfc, out);
}

// Round 7
// 952.093 us; speedup vs baseline: 1.1634x; 1.0272x over previous
//
#include <hip/hip_runtime.h>
#include <hip/hip_bf16.h>
#include <math.h>

// Model: B=64,S=100,D=768,H=8,P=8,FF=3072,HD=96, 4 shared layers.
//  - param path computed ONCE (layer-shared); param_bias via MFMA (R4).
//  - GEMM gemm256 (R11): R10's fine-interleaved schedule (tri-buffer BK=32,
//    counted vmcnt(3), setprio, 1 barrier/tile, chunk-XOR swizzle) with
//    BM/BN swapped to 128x256: same grids (600/150), same 72KB LDS and
//    2 blocks/CU, but A re-read 12x instead of 24x (gemm<1>) / 3x instead
//    of 6x (gemm<2>) -> L2-miss (FETCH) traffic ~halves; miss-latency
//    stalls shrink. Wave grid 2Mx4N, per-wave 64x64 unchanged.
//  - R11 non-GEMM sweep: PE table (trig 4.9M->77K evals), pool_mean float4,
//    ln_row one-pass sum/sumsq reduction (4->2 barriers), attn float4 staging.
//  - attention per (b,h): MFMA scores (pbias C-init) + reg-softmax + MFMA PV.
//  - split-K classifier.

typedef __attribute__((ext_vector_type(8))) short bf16x8;
typedef __attribute__((ext_vector_type(4))) float f32x4;
typedef __attribute__((ext_vector_type(4))) short short4v;

#define BB 64
#define SS 100
#define DD 768
#define HH 8
#define HD 96
#define FF_ 3072
#define ROWS 6400           // B*S
#define LN10000 9.210340371976184f

__device__ __forceinline__ void async_copy16(void* lds_dst, const void* gsrc) {
  __builtin_amdgcn_global_load_lds(
      (const __attribute__((address_space(1))) void*)gsrc,
      (__attribute__((address_space(3))) void*)lds_dst, 16, 0, 0);
}

// ---------------- block-wide sums ----------------
__device__ __forceinline__ float block_sum256(float v, float* sbuf) {
#pragma unroll
  for (int o = 32; o > 0; o >>= 1) v += __shfl_xor(v, o, 64);
  int tid = threadIdx.x;
  __syncthreads();
  if ((tid & 63) == 0) sbuf[tid >> 6] = v;
  __syncthreads();
  return sbuf[0] + sbuf[1] + sbuf[2] + sbuf[3];
}

// one-pass paired reduction over 192 threads: returns (S1,S2) via refs
__device__ __forceinline__ void block_sum192_pair(float v1, float v2,
                                                  float* sbuf,
                                                  float& S1, float& S2) {
#pragma unroll
  for (int o = 32; o > 0; o >>= 1) {
    v1 += __shfl_xor(v1, o, 64);
    v2 += __shfl_xor(v2, o, 64);
  }
  int tid = threadIdx.x;
  __syncthreads();
  if ((tid & 63) == 0) {
    sbuf[2 * (tid >> 6)] = v1;
    sbuf[2 * (tid >> 6) + 1] = v2;
  }
  __syncthreads();
  S1 = sbuf[0] + sbuf[2] + sbuf[4];
  S2 = sbuf[1] + sbuf[3] + sbuf[5];
}

// ---------------- fp32 [K,N] -> bf16 [N,K] transpose-convert ----------------
__global__ void convert_transpose(const float* __restrict__ in,
                                  __hip_bfloat16* __restrict__ out,
                                  int K, int N) {
  __shared__ float t[32][33];
  int n0 = blockIdx.x * 32, k0 = blockIdx.y * 32;
  int tid = threadIdx.x;
  int tx = tid & 31, ty = tid >> 5;  // ty 0..7
#pragma unroll
  for (int j = 0; j < 32; j += 8)
    t[ty + j][tx] = in[(size_t)(k0 + ty + j) * N + n0 + tx];
  __syncthreads();
#pragma unroll
  for (int j = 0; j < 32; j += 8)
    out[(size_t)(n0 + ty + j) * K + k0 + tx] = __float2bfloat16(t[tx][ty + j]);
}

// ---------------- pooled = mean_P(param_seq) -> bf16 (float4) ----------------
__global__ void pool_mean(const float* __restrict__ ps,
                          __hip_bfloat16* __restrict__ pooled) {
  int idx4 = blockIdx.x * 256 + threadIdx.x;  // < 6400*768/4
  int row = idx4 / 192, c4 = (idx4 - row * 192) * 4;
  float4 s = {0.f, 0.f, 0.f, 0.f};
#pragma unroll
  for (int p = 0; p < 8; p++) {
    float4 v = *(const float4*)(ps + (size_t)(row * 8 + p) * DD + c4);
    s.x += v.x; s.y += v.y; s.z += v.z; s.w += v.w;
  }
  __hip_bfloat16 hb[4] = {__float2bfloat16(s.x * 0.125f), __float2bfloat16(s.y * 0.125f),
                          __float2bfloat16(s.z * 0.125f), __float2bfloat16(s.w * 0.125f)};
  *(short4v*)(pooled + (size_t)row * DD + c4) = *(short4v*)hb;
}

// ---------------- PE table (trig once per (s,c), not per (b,s,c)) ----------
__global__ void pe_build(float* __restrict__ pet) {
  int idx = blockIdx.x * 256 + threadIdx.x;  // < SS*DD
  if (idx >= SS * DD) return;
  int srow = idx / DD, c = idx - srow * DD;
  int c2 = c & ~1;
  float ang = (float)srow * expf((float)c2 * (-LN10000 / (float)DD));
  pet[idx] = (c & 1) ? cosf(ang) : sinf(ang);
}

// ---------------- src = template + PE (float4, table) ----------------
__global__ void add_pe(const float* __restrict__ t, const float* __restrict__ pet,
                       float* __restrict__ src) {
  int idx4 = blockIdx.x * 256 + threadIdx.x;  // < 6400*768/4
  int row = idx4 / 192, c4 = (idx4 - row * 192) * 4;
  int srow = row % SS;
  float4 tv = *(const float4*)(t + (size_t)row * DD + c4);
  float4 pv = *(const float4*)(pet + (size_t)srow * DD + c4);
  tv.x += pv.x; tv.y += pv.y; tv.z += pv.z; tv.w += pv.w;
  *(float4*)(src + (size_t)row * DD + c4) = tv;
}

// ---------------- LayerNorm over rows of 768 (192 thr, float4) ----------------
// XB16: X is bf16; RESID: add R (fp32); WB16: also write bf16 copy
// R11: one-pass sum/sumsq (var = E[x^2]-mean^2), 2 barriers instead of 4.
template <bool XB16, bool RESID, bool WB16>
__global__ void ln_row(const float* __restrict__ Xf,
                       const __hip_bfloat16* __restrict__ Xb,
                       const float* __restrict__ R,
                       const float* __restrict__ g, const float* __restrict__ bb,
                       float* __restrict__ of, __hip_bfloat16* __restrict__ ob) {
  int row = blockIdx.x, tid = threadIdx.x;
  size_t base = (size_t)row * DD;
  int c4 = tid * 4;
  float4 v;
  if constexpr (XB16) {
    short4v xv = *(const short4v*)(Xb + base + c4);
    __hip_bfloat16* p = (__hip_bfloat16*)&xv;
    v.x = __bfloat162float(p[0]); v.y = __bfloat162float(p[1]);
    v.z = __bfloat162float(p[2]); v.w = __bfloat162float(p[3]);
  } else {
    v = *(const float4*)(Xf + base + c4);
  }
  if (RESID) {
    float4 rv = *(const float4*)(R + base + c4);
    v.x += rv.x; v.y += rv.y; v.z += rv.z; v.w += rv.w;
  }
  __shared__ float sbuf[6];
  float S1, S2;
  block_sum192_pair(v.x + v.y + v.z + v.w,
                    v.x * v.x + v.y * v.y + v.z * v.z + v.w * v.w,
                    sbuf, S1, S2);
  float mean = S1 * (1.0f / DD);
  float var = S2 * (1.0f / DD) - mean * mean;
  float rs = rsqrtf(var + 1e-5f);
  float dx = v.x - mean, dy = v.y - mean, dz = v.z - mean, dw = v.w - mean;
  float4 gv = *(const float4*)(g + c4);
  float4 bv = *(const float4*)(bb + c4);
  float4 y;
  y.x = dx * rs * gv.x + bv.x;
  y.y = dy * rs * gv.y + bv.y;
  y.z = dz * rs * gv.z + bv.z;
  y.w = dw * rs * gv.w + bv.w;
  *(float4*)(of + base + c4) = y;
  if (WB16) {
    __hip_bfloat16 hb[4] = {__float2bfloat16(y.x), __float2bfloat16(y.y),
                            __float2bfloat16(y.z), __float2bfloat16(y.w)};
    *(short4v*)(ob + base + c4) = *(short4v*)hb;
  }
}

// ---------------- param_bias via MFMA: pb.pb^T / sqrt(HD) ----------------
__launch_bounds__(256, 2)
__global__ void param_bias_mfma(const float* __restrict__ penc,
                                float* __restrict__ pbias) {
  __shared__ __align__(16) __hip_bfloat16 Qs[128][104];
  const int bh = blockIdx.x;
  const int b = bh >> 3, h = bh & 7;
  const int tid = threadIdx.x;
  const int wave = tid >> 6, lane = tid & 63;
  const int r = lane & 15, quad = lane >> 4;
  const int q8 = quad * 8;
  const int wr = (wave >> 1) * 64, wc = (wave & 1) * 64;
  const float sroot = rsqrtf(9.79795897113f);  // 96^(-1/4)
  for (int i = tid; i < 128 * HD; i += 256) {
    int s = i / HD, d = i - s * HD;
    float v = (s < SS) ? penc[(size_t)(b * SS + s) * DD + h * HD + d] : 0.f;
    Qs[s][d] = __float2bfloat16(v * sroot);
  }
  __syncthreads();
  f32x4 acc[4][4] = {};
#pragma unroll
  for (int k0 = 0; k0 < HD; k0 += 32) {
    bf16x8 af[4], bfv[4];
#pragma unroll
    for (int mi = 0; mi < 4; mi++)
      af[mi] = *(const bf16x8*)&Qs[wr + mi * 16 + r][k0 + q8];
#pragma unroll
    for (int ni = 0; ni < 4; ni++)
      bfv[ni] = *(const bf16x8*)&Qs[wc + ni * 16 + r][k0 + q8];
#pragma unroll
    for (int mi = 0; mi < 4; mi++)
#pragma unroll
      for (int ni = 0; ni < 4; ni++)
        acc[mi][ni] = __builtin_amdgcn_mfma_f32_16x16x32_bf16(af[mi], bfv[ni],
                                                              acc[mi][ni], 0, 0, 0);
  }
  float* pb = pbias + (size_t)bh * SS * SS;
#pragma unroll
  for (int mi = 0; mi < 4; mi++)
#pragma unroll
    for (int ni = 0; ni < 4; ni++) {
      int col = wc + ni * 16 + r;
      if (col < SS) {
#pragma unroll
        for (int rg = 0; rg < 4; rg++) {
          int row = wr + mi * 16 + quad * 4 + rg;
          if (row < SS) pb[row * SS + col] = acc[mi][ni][rg];
        }
      }
    }
}

// ---------------- fused MFMA attention per (b,h) ----------------
__launch_bounds__(256, 2)
__global__ void attn_fused_mfma(const float* __restrict__ src,
                                const float* __restrict__ pbias,
                                __hip_bfloat16* __restrict__ out) {
  __shared__ __align__(16) char umem[128 * 136 * 2];  // Qs[128][104] then Ps[128][136]
  __shared__ __align__(16) __hip_bfloat16 Qt[96][136];
  __shared__ float redm[2][128];
  __shared__ float reds[2][128];
  __hip_bfloat16 (*Qs)[104] = (__hip_bfloat16 (*)[104])umem;
  __hip_bfloat16 (*Ps)[136] = (__hip_bfloat16 (*)[136])umem;

  const int bh = blockIdx.x;
  const int b = bh >> 3, h = bh & 7;
  const int tid = threadIdx.x;
  const int wave = tid >> 6, lane = tid & 63;
  const int r = lane & 15, quad = lane >> 4;
  const int q8 = quad * 8;
  const int wr = (wave >> 1) * 64, wc = (wave & 1) * 64;

  const float sroot = rsqrtf(9.79795897113f);  // 96^(-1/4)
  // vectorized staging: 100 rows x 24 float4 each
  for (int i = tid; i < SS * (HD / 4); i += 256) {
    int s = i / 24, j = i - s * 24;
    float4 v4 = *(const float4*)(src + (size_t)(b * SS + s) * DD + h * HD + j * 4);
    __hip_bfloat16 hb[4] = {__float2bfloat16(v4.x * sroot), __float2bfloat16(v4.y * sroot),
                            __float2bfloat16(v4.z * sroot), __float2bfloat16(v4.w * sroot)};
    *(short4v*)&Qs[s][j * 4] = *(short4v*)hb;
    Qt[j * 4 + 0][s] = __float2bfloat16(v4.x);
    Qt[j * 4 + 1][s] = __float2bfloat16(v4.y);
    Qt[j * 4 + 2][s] = __float2bfloat16(v4.z);
    Qt[j * 4 + 3][s] = __float2bfloat16(v4.w);
  }
  {  // zero pads (vectorized): Qs rows 100..127; Qt cols 100..127
    __hip_bfloat16 zb[4] = {__float2bfloat16(0.f), __float2bfloat16(0.f),
                            __float2bfloat16(0.f), __float2bfloat16(0.f)};
    short4v z4 = *(short4v*)zb;
    for (int i = tid; i < 28 * 24; i += 256) {          // 672 slots
      int s = i / 24, j = i - s * 24;
      *(short4v*)&Qs[100 + s][j * 4] = z4;
    }
    for (int i = tid; i < 96 * 7; i += 256) {           // 672 slots
      int d = i / 7, j = i - d * 7;
      *(short4v*)&Qt[d][100 + j * 4] = z4;              // cols 100..127
    }
  }

  const float* pb = pbias + (size_t)bh * SS * SS;
  bool cv[4]; int cols[4];
#pragma unroll
  for (int ni = 0; ni < 4; ni++) { cols[ni] = wc + ni * 16 + r; cv[ni] = cols[ni] < SS; }
  f32x4 acc[4][4];
#pragma unroll
  for (int mi = 0; mi < 4; mi++)
#pragma unroll
    for (int rg = 0; rg < 4; rg++) {
      int row = wr + mi * 16 + quad * 4 + rg;
#pragma unroll
      for (int ni = 0; ni < 4; ni++)
        acc[mi][ni][rg] = (row < SS && cv[ni]) ? pb[row * SS + cols[ni]] : 0.f;
    }
  __syncthreads();

#pragma unroll
  for (int k0 = 0; k0 < HD; k0 += 32) {
    bf16x8 af[4], bfv[4];
#pragma unroll
    for (int mi = 0; mi < 4; mi++)
      af[mi] = *(const bf16x8*)&Qs[wr + mi * 16 + r][k0 + q8];
#pragma unroll
    for (int ni = 0; ni < 4; ni++)
      bfv[ni] = *(const bf16x8*)&Qs[wc + ni * 16 + r][k0 + q8];
#pragma unroll
    for (int mi = 0; mi < 4; mi++)
#pragma unroll
      for (int ni = 0; ni < 4; ni++)
        acc[mi][ni] = __builtin_amdgcn_mfma_f32_16x16x32_bf16(af[mi], bfv[ni],
                                                              acc[mi][ni], 0, 0, 0);
  }

  float mx[4][4];
#pragma unroll
  for (int mi = 0; mi < 4; mi++)
#pragma unroll
    for (int rg = 0; rg < 4; rg++) {
      float m = -1e30f;
#pragma unroll
      for (int ni = 0; ni < 4; ni++)
        if (cv[ni]) m = fmaxf(m, acc[mi][ni][rg]);
#pragma unroll
      for (int o = 1; o < 16; o <<= 1) m = fmaxf(m, __shfl_xor(m, o, 64));
      mx[mi][rg] = m;
    }
  if (r == 0) {
#pragma unroll
    for (int mi = 0; mi < 4; mi++)
#pragma unroll
      for (int rg = 0; rg < 4; rg++)
        redm[wave & 1][wr + mi * 16 + quad * 4 + rg] = mx[mi][rg];
  }
  __syncthreads();

#pragma unroll
  for (int mi = 0; mi < 4; mi++)
#pragma unroll
    for (int rg = 0; rg < 4; rg++) {
      int row = wr + mi * 16 + quad * 4 + rg;
      float rmax = fmaxf(redm[0][row], redm[1][row]);
      float s = 0.f;
#pragma unroll
      for (int ni = 0; ni < 4; ni++) {
        float e = cv[ni] ? __expf(acc[mi][ni][rg] - rmax) : 0.f;
        acc[mi][ni][rg] = e;
        s += e;
      }
#pragma unroll
      for (int o = 1; o < 16; o <<= 1) s += __shfl_xor(s, o, 64);
      if (r == 0) reds[wave & 1][row] = s;
    }
  __syncthreads();

#pragma unroll
  for (int mi = 0; mi < 4; mi++)
#pragma unroll
    for (int rg = 0; rg < 4; rg++) {
      int row = wr + mi * 16 + quad * 4 + rg;
      float inv = 1.0f / (reds[0][row] + reds[1][row]);
#pragma unroll
      for (int ni = 0; ni < 4; ni++)
        Ps[row][cols[ni]] = __float2bfloat16(acc[mi][ni][rg] * inv);
    }
  __syncthreads();

  const int wr2 = (wave >> 1) * 48;
  f32x4 po[3][4] = {};
#pragma unroll
  for (int kk = 0; kk < 128; kk += 32) {
    bf16x8 aq[3], bp[4];
#pragma unroll
    for (int mi = 0; mi < 3; mi++)
      aq[mi] = *(const bf16x8*)&Qt[wr2 + mi * 16 + r][kk + q8];
#pragma unroll
    for (int ni = 0; ni < 4; ni++)
      bp[ni] = *(const bf16x8*)&Ps[wc + ni * 16 + r][kk + q8];
#pragma unroll
    for (int mi = 0; mi < 3; mi++)
#pragma unroll
      for (int ni = 0; ni < 4; ni++)
        po[mi][ni] = __builtin_amdgcn_mfma_f32_16x16x32_bf16(aq[mi], bp[ni],
                                                             po[mi][ni], 0, 0, 0);
  }
#pragma unroll
  for (int mi = 0; mi < 3; mi++)
#pragma unroll
    for (int ni = 0; ni < 4; ni++) {
      int qcol = wc + ni * 16 + r;
      if (qcol < SS) {
        int d0 = wr2 + mi * 16 + quad * 4;
        __hip_bfloat16 hb[4];
#pragma unroll
        for (int rg = 0; rg < 4; rg++) hb[rg] = __float2bfloat16(po[mi][ni][rg]);
        *(short4v*)(out + (size_t)(b * SS + qcol) * DD + h * HD + d0) = *(short4v*)hb;
      }
    }
}

// ---------------- bf16 MFMA GEMM (R11): C[M,N] = A[M,K] @ Bt[N,K]^T --------
// MODE 0: outf = C + bias; MODE 1: outb = gelu(C + bias) bf16; MODE 2: outf = C + bias + resid
// 128x256 tile (BM/BN swapped vs R10 to halve A re-reads -> FETCH), BK=32,
// 8 waves (2Mx4N, 64x64/wave), tri-buffered LDS 72KB -> 2 blocks/CU.
// Per K-tile: {8 ds_read_b128 || 3 global_load_lds of tile t+2 || setprio+
// 16 MFMA || vmcnt(3); s_barrier; sched_barrier}. FIFO vmcnt(3): tile t+1's
// 3 loads complete, t+2's stay in flight. Tri-buffer race-free (slot (t+2)%3
// last read in tile t-1, barrier-separated). Chunk-XOR swizzle (R5-proven):
// stored chunk c holds global chunk c^((row>>1)&3); read XORs same key.
template <int MODE>
__launch_bounds__(512, 4)
__global__ void gemm256(const __hip_bfloat16* __restrict__ A,
                        const __hip_bfloat16* __restrict__ Bt,
                        const float* __restrict__ bias,
                        const float* __restrict__ resid,
                        float* __restrict__ outf,
                        __hip_bfloat16* __restrict__ outb,
                        int M, int N, int K) {
  constexpr int BM = 128, BN = 256, BK = 32;
  __shared__ __align__(16) __hip_bfloat16 As[3][BM * BK];  // 24 KB
  __shared__ __align__(16) __hip_bfloat16 Bs[3][BN * BK];  // 48 KB
  const int gm = M >> 7, gn = N >> 8;
  const int nwg = gm * gn;
  // bijective XCD swizzle (m204): contiguous chunk per XCD, any nwg
  int wg = (int)blockIdx.x;
  {
    int qc = nwg >> 3, rc = nwg & 7;
    int xcd = wg & 7, pos = wg >> 3;
    wg = (xcd < rc ? xcd * (qc + 1) : rc * (qc + 1) + (xcd - rc) * qc) + pos;
  }
  const int nt0 = wg / gm, mt = wg - nt0 * gm;   // m fastest: same B-panel per run
  const int m0 = mt * BM, n0 = nt0 * BN;
  const int tid = threadIdx.x;
  const int wave = tid >> 6, lane = tid & 63;
  const int wm = wave >> 2, wn = wave & 3;       // 2M x 4N wave grid
  const int r = lane & 15, q = lane >> 4;        // q in 0..3 = 16B chunk of BK=32

  // ---- staging: 3 x 16B chunks per thread per K-tile (A:1, B:2) ----
  const int srow = tid >> 2;                     // 0..127
  const int scp = (tid & 3) ^ ((srow >> 1) & 3); // swizzled source chunk
  const __hip_bfloat16* gA0 = A + (size_t)(m0 + srow) * K + scp * 8;
  const __hip_bfloat16* gB0 = Bt + (size_t)(n0 + srow) * K + scp * 8;
  const __hip_bfloat16* gB1 = Bt + (size_t)(n0 + srow + 128) * K + scp * 8;  // key invariant under +128

  // ---- frag read offsets (elements) ----
  const int key8 = ((r >> 1) & 3) * 8;
  const int cq = (q * 8) ^ key8;                 // swizzled chunk for this lane
  const int aBase = wm * 2048 + r * 32;          // (wm*64 + r) * 32
  const int bBase = wn * 2048 + r * 32;          // (wn*64 + r) * 32

  f32x4 acc[4][4] = {};

  const int NT = K / BK;
  // prologue: stage tiles 0 and 1
#pragma unroll
  for (int t = 0; t < 2; ++t) {
    const int kel = t * BK;
    async_copy16(&As[t][tid * 8],          gA0 + kel);
    async_copy16(&Bs[t][tid * 8],          gB0 + kel);
    async_copy16(&Bs[t][(tid + 512) * 8],  gB1 + kel);
  }
  asm volatile("s_waitcnt vmcnt(3)" ::: "memory");  // tile 0 resident
  __builtin_amdgcn_s_barrier();
  __builtin_amdgcn_sched_barrier(0);

  int slot = 0;
  for (int t = 0; t < NT; ++t) {
    const int s2 = (slot >= 1) ? slot - 1 : slot + 2;  // (t+2)%3
    const bool st = (t + 2 < NT);
    const int kel = (t + 2) * BK;
    bf16x8 af[4], bfr[4];
#pragma unroll
    for (int mi = 0; mi < 4; mi++)
      af[mi] = *(const bf16x8*)(&As[slot][aBase + mi * 512 + cq]);
#pragma unroll
    for (int ni = 0; ni < 4; ni++)
      bfr[ni] = *(const bf16x8*)(&Bs[slot][bBase + ni * 512 + cq]);
    if (st) {
      async_copy16(&As[s2][tid * 8],         gA0 + kel);
      async_copy16(&Bs[s2][tid * 8],         gB0 + kel);
      async_copy16(&Bs[s2][(tid + 512) * 8], gB1 + kel);
    }
    __builtin_amdgcn_s_setprio(1);
#pragma unroll
    for (int mi = 0; mi < 4; mi++)
#pragma unroll
      for (int ni = 0; ni < 4; ni++)
        acc[mi][ni] = __builtin_amdgcn_mfma_f32_16x16x32_bf16(af[mi], bfr[ni],
                                                              acc[mi][ni], 0, 0, 0);
    __builtin_amdgcn_s_setprio(0);
    if (st) asm volatile("s_waitcnt vmcnt(3)" ::: "memory");  // t+1 resident
    else    asm volatile("s_waitcnt vmcnt(0)" ::: "memory");  // tail drain
    __builtin_amdgcn_s_barrier();
    __builtin_amdgcn_sched_barrier(0);
    slot = (slot == 2) ? 0 : slot + 1;
  }

  // ---- epilogue ----
#pragma unroll
  for (int mi = 0; mi < 4; mi++) {
#pragma unroll
    for (int ni = 0; ni < 4; ni++) {
      int col = n0 + wn * 64 + ni * 16 + r;
      float bv = bias[col];
#pragma unroll
      for (int rg = 0; rg < 4; rg++) {
        int row = m0 + wm * 64 + mi * 16 + q * 4 + rg;
        size_t oidx = (size_t)row * N + col;
        float v = acc[mi][ni][rg] + bv;
        if constexpr (MODE == 2) v += resid[oidx];
        if constexpr (MODE == 1) {
          v = 0.5f * v * (1.0f + erff(v * 0.70710678118654752f));
          outb[oidx] = __float2bfloat16(v);
        } else {
          outf[oidx] = v;
        }
      }
    }
  }
}

// ---------------- split-K classifier ----------------
#define CCHUNK 3072
#define NCHUNK 25   // 76800 / 3072
__global__ void classifier_part(const float* __restrict__ x,
                                const float* __restrict__ Wfc,
                                float* __restrict__ part) {
  int chunk = blockIdx.x, b = blockIdx.y, tid = threadIdx.x;
  const float* xb = x + (size_t)b * (SS * DD) + chunk * CCHUNK;
  const float* w = Wfc + 2 * (size_t)chunk * CCHUNK;
  float a0 = 0.f, a1 = 0.f;
  for (int i = tid; i < CCHUNK; i += 256) {
    float xv = xb[i];
    float2 wv = *(const float2*)(w + 2 * i);
    a0 += xv * wv.x;
    a1 += xv * wv.y;
  }
  __shared__ float sbuf[4];
  a0 = block_sum256(a0, sbuf);
  a1 = block_sum256(a1, sbuf);
  if (tid == 0) {
    part[(b * NCHUNK + chunk) * 2] = a0;
    part[(b * NCHUNK + chunk) * 2 + 1] = a1;
  }
}

__global__ void classifier_final(const float* __restrict__ part,
                                 const float* __restrict__ bfc,
                                 float* __restrict__ out) {
  int b = threadIdx.x;  // 64 threads
  float a0 = bfc[0], a1 = bfc[1];
#pragma unroll
  for (int c = 0; c < NCHUNK; c++) {
    a0 += part[(b * NCHUNK + c) * 2];
    a1 += part[(b * NCHUNK + c) * 2 + 1];
  }
  out[2 * b] = a0;
  out[2 * b + 1] = a1;
}

// ---------------- launcher ----------------
extern "C" void kernel_launch(void* const* d_in, const int* in_sizes, int n_in,
                              void* d_out, int out_size, void* d_ws, size_t ws_size,
                              hipStream_t stream) {
  const float* Tmpl = (const float*)d_in[0];
  const float* Pseq = (const float*)d_in[1];
  const float* Wc   = (const float*)d_in[2];
  const float* bc   = (const float*)d_in[3];
  const float* gp   = (const float*)d_in[4];
  const float* bp   = (const float*)d_in[5];
  const float* W1   = (const float*)d_in[6];
  const float* b1   = (const float*)d_in[7];
  const float* W2   = (const float*)d_in[8];
  const float* b2   = (const float*)d_in[9];
  const float* g1   = (const float*)d_in[10];
  const float* bn1  = (const float*)d_in[11];
  const float* g2   = (const float*)d_in[12];
  const float* bn2  = (const float*)d_in[13];
  const float* Wfc  = (const float*)d_in[14];
  const float* bfc  = (const float*)d_in[15];
  float* out = (float*)d_out;
  (void)in_sizes; (void)n_in; (void)out_size; (void)ws_size;

  char* ws = (char*)d_ws;
  size_t off = 0;
  auto alloc = [&](size_t n) { size_t o = off; off += (n + 255) & ~(size_t)255; return o; };

  __hip_bfloat16* Wct = (__hip_bfloat16*)(ws + alloc((size_t)768 * 768 * 2));
  __hip_bfloat16* W1t = (__hip_bfloat16*)(ws + alloc((size_t)768 * 3072 * 2));
  __hip_bfloat16* W2t = (__hip_bfloat16*)(ws + alloc((size_t)3072 * 768 * 2));
  size_t h1_off = alloc((size_t)ROWS * FF_ * 2);
  __hip_bfloat16* h1 = (__hip_bfloat16*)(ws + h1_off);
  float* param_enc = (float*)(ws + h1_off);            // alias: dead before h1 live
  size_t slb_off = alloc((size_t)ROWS * DD * 2);
  __hip_bfloat16* src_ln_bf = (__hip_bfloat16*)(ws + slb_off);
  __hip_bfloat16* pooled = (__hip_bfloat16*)(ws + slb_off);  // alias
  size_t ao_off = alloc((size_t)ROWS * DD * 4);
  __hip_bfloat16* attn_out_b = (__hip_bfloat16*)(ws + ao_off);
  float* pe_lin = (float*)(ws + ao_off);               // alias
  float* pbias = (float*)(ws + alloc((size_t)512 * SS * SS * 4));
  float* src = (float*)(ws + alloc((size_t)ROWS * DD * 4));
  float* src_ln = (float*)(ws + alloc((size_t)ROWS * DD * 4));
  float* z = (float*)(ws + alloc((size_t)ROWS * DD * 4));
  float* cpart = (float*)(ws + alloc((size_t)BB * NCHUNK * 2 * 4));
  float* pet = (float*)(ws + alloc((size_t)SS * DD * 4));

  // ---- layer-invariant precompute ----
  convert_transpose<<<dim3(768 / 32, 768 / 32), 256, 0, stream>>>(Wc, Wct, 768, 768);
  convert_transpose<<<dim3(3072 / 32, 768 / 32), 256, 0, stream>>>(W1, W1t, 768, 3072);
  convert_transpose<<<dim3(768 / 32, 3072 / 32), 256, 0, stream>>>(W2, W2t, 3072, 768);
  pe_build<<<(SS * DD + 255) / 256, 256, 0, stream>>>(pet);
  pool_mean<<<ROWS * DD / 4 / 256, 256, 0, stream>>>(Pseq, pooled);
  gemm256<0><<<(DD / 256) * (ROWS / 128), 512, 0, stream>>>(
      pooled, Wct, bc, nullptr, pe_lin, nullptr, ROWS, DD, 768);
  ln_row<false, false, false><<<ROWS, 192, 0, stream>>>(
      pe_lin, nullptr, nullptr, gp, bp, param_enc, nullptr);
  param_bias_mfma<<<512, 256, 0, stream>>>(param_enc, pbias);
  add_pe<<<ROWS * DD / 4 / 256, 256, 0, stream>>>(Tmpl, pet, src);

  // ---- 4 shared layers ----
  for (int l = 0; l < 4; ++l) {
    attn_fused_mfma<<<512, 256, 0, stream>>>(src, pbias, attn_out_b);
    ln_row<true, true, true><<<ROWS, 192, 0, stream>>>(
        nullptr, attn_out_b, src, g1, bn1, src_ln, src_ln_bf);
    gemm256<1><<<(FF_ / 256) * (ROWS / 128), 512, 0, stream>>>(
        src_ln_bf, W1t, b1, nullptr, nullptr, h1, ROWS, FF_, DD);
    gemm256<2><<<(DD / 256) * (ROWS / 128), 512, 0, stream>>>(
        h1, W2t, b2, src_ln, z, nullptr, ROWS, DD, FF_);
    ln_row<false, false, false><<<ROWS, 192, 0, stream>>>(
        z, nullptr, nullptr, g2, bn2, src, nullptr);
  }

  classifier_part<<<dim3(NCHUNK, BB), 256, 0, stream>>>(src, Wfc, cpart);
  classifier_final<<<1, 64, 0, stream>>>(cpart, bfc, out);
}